// Round 6
// baseline (252.009 us; speedup 1.0000x reference)
//
#include <hip/hip_runtime.h>
#include <math.h>

// Problem constants (B=4, T=2048, C=576, H=12, D=48)
#define Bn 4
#define Tn 2048
#define Cn 576
#define Hn 12
#define Dn 48
#define Mn (Bn*Tn)          // 8192 rows

// log2(e) / sqrt(48) — folded into q so attention uses exp2 directly
#define QSCALE (1.4426950408889634f * 0.14433756729740643f)

typedef short  short8  __attribute__((ext_vector_type(8)));   // 8 bf16 (4 VGPRs)
typedef float  floatx4 __attribute__((ext_vector_type(4)));   // MFMA acc
typedef unsigned short ushort_t;

static __device__ __forceinline__ unsigned short f2bf(float f) {
    union { float f; unsigned int u; } v; v.f = f;
    unsigned int r = v.u + 0x7FFFu + ((v.u >> 16) & 1u);   // round-to-nearest-even
    return (unsigned short)(r >> 16);
}

// truncation-pack two fp32 -> packed bf16x2 (P >= 0, rel err <= 2^-8)
static __device__ __forceinline__ unsigned int pack_trunc(float a, float b) {
    union { float f; unsigned int u; } ua, ub; ua.f = a; ub.f = b;
    return (ua.u >> 16) | (ub.u & 0xFFFF0000u);
}

// async global->LDS, 16B per lane; lane l's data lands at lds + l*16 (lane-linear)
static __device__ __forceinline__ void gload16(void* lds, const void* g) {
    __builtin_amdgcn_global_load_lds(
        (const __attribute__((address_space(1))) void*)g,
        (__attribute__((address_space(3))) void*)lds, 16, 0, 0);
}

// ---------------------------------------------------------------------------
// fused fp32 -> bf16 cast of all three inputs (one launch)
// ---------------------------------------------------------------------------
__global__ __launch_bounds__(256)
void cast3(const float* __restrict__ a, ushort_t* __restrict__ oa, int na4,
           const float* __restrict__ b, ushort_t* __restrict__ ob, int nb4,
           const float* __restrict__ c, ushort_t* __restrict__ oc, int nc4)
{
    int i = blockIdx.x * 256 + threadIdx.x;
    const float* src; ushort_t* dst; int idx;
    if (i < na4)                  { src = a; dst = oa; idx = i; }
    else if (i < na4 + nb4)       { src = b; dst = ob; idx = i - na4; }
    else if (i < na4 + nb4 + nc4) { src = c; dst = oc; idx = i - na4 - nb4; }
    else return;
    float4 v = ((const float4*)src)[idx];
    ushort4 o;
    o.x = f2bf(v.x); o.y = f2bf(v.y); o.z = f2bf(v.z); o.w = f2bf(v.w);
    ((ushort4*)dst)[idx] = o;
}

// ---------------------------------------------------------------------------
// BARRIER-FREE MFMA bf16 GEMM: out = A[M,576] @ W[N,576]^T.
// Each WAVE owns an independent 64x64 tile (wave-private LDS double buffer,
// 8 segs x 1KB per buf). Staging via global_load_lds (lane-linear frag order).
// Ring sync: issue next K-step's 8 loads, then s_waitcnt vmcnt(8) -> waits only
// this wave's previous 8. No s_barrier anywhere -> no convoy; 10 waves/CU
// interleave to hide latency. Block = 128 thr (2 independent waves).
// MODE 0: scatter q (xQSCALE) / k -> [B,H,T,48]; v -> transposed [B,H,48,T]
// MODE 1: fp32 row-major [M,576]
// ---------------------------------------------------------------------------
template<int MODE, int NB>
__global__ __launch_bounds__(128)
void gemm_mfma(const ushort_t* __restrict__ A, const ushort_t* __restrict__ W,
               ushort_t* __restrict__ outb, float* __restrict__ outf)
{
    __shared__ __align__(16) ushort_t Ls[2][2][8][512];   // [wave][buf][seg][..] 32KB

    const int tid  = threadIdx.x;
    const int wave = tid >> 6;
    const int lane = tid & 63;
    const int m    = lane & 15;
    const int g    = lane >> 4;
    const int wid  = blockIdx.x * 2 + wave;
    const int n0   = (wid % NB) * 64;
    const int m0   = (wid / NB) * 64;

    floatx4 acc[4][4];
    #pragma unroll
    for (int i = 0; i < 4; ++i)
        #pragma unroll
        for (int j = 0; j < 4; ++j)
            acc[i][j] = (floatx4){0.f, 0.f, 0.f, 0.f};

    // per-lane global pointers, frag order: seg s<4 = A rows, s>=4 = W rows
    const char* gp[8];
    #pragma unroll
    for (int s = 0; s < 4; ++s) {
        gp[s]     = (const char*)(A + (size_t)(m0 + s * 16 + m) * Cn) + g * 16;
        gp[4 + s] = (const char*)(W + (size_t)(n0 + s * 16 + m) * Cn) + g * 16;
    }

    // prologue: stage K-step 0 into buf 0
    #pragma unroll
    for (int s = 0; s < 8; ++s) { gload16(&Ls[wave][0][s][0], gp[s]); gp[s] += 64; }

    for (int k = 0; k < Cn / 32; ++k) {
        const int cur = k & 1;
        if (k < Cn / 32 - 1) {
            #pragma unroll
            for (int s = 0; s < 8; ++s) { gload16(&Ls[wave][cur ^ 1][s][0], gp[s]); gp[s] += 64; }
            asm volatile("s_waitcnt vmcnt(8)" ::: "memory");   // cur buf's 8 done
        } else {
            asm volatile("s_waitcnt vmcnt(0)" ::: "memory");
        }
        short8 af[4], bf4[4];
        #pragma unroll
        for (int i = 0; i < 4; ++i) af[i]  = *(const short8*)&Ls[wave][cur][i][lane * 8];
        #pragma unroll
        for (int j = 0; j < 4; ++j) bf4[j] = *(const short8*)&Ls[wave][cur][4 + j][lane * 8];
        #pragma unroll
        for (int i = 0; i < 4; ++i)
            #pragma unroll
            for (int j = 0; j < 4; ++j)
                acc[i][j] = __builtin_amdgcn_mfma_f32_16x16x32_bf16(af[i], bf4[j], acc[i][j], 0, 0, 0);
    }

    // epilogue: C/D layout col = lane&15 (n), row = (lane>>4)*4 + reg (m)
    const size_t per = (size_t)Bn * Hn * Tn * Dn;
    if (MODE == 0) {
        const int which = n0 / Cn;                 // 64-col tile fits in one of q/k/v
        const int nb    = n0 - which * Cn;
        #pragma unroll
        for (int i = 0; i < 4; ++i) {
            int mrow0 = m0 + i * 16 + g * 4;
            int b  = mrow0 >> 11;
            int t0 = mrow0 & 2047;
            #pragma unroll
            for (int j = 0; j < 4; ++j) {
                int n = nb + j * 16 + m;
                int h = n / 48;
                int d = n - h * 48;
                if (which == 2) {
                    ushort4 pk;
                    pk.x = f2bf(acc[i][j][0]); pk.y = f2bf(acc[i][j][1]);
                    pk.z = f2bf(acc[i][j][2]); pk.w = f2bf(acc[i][j][3]);
                    *(ushort4*)&outb[2 * per + (((size_t)(b * Hn + h) * Dn + d) * Tn) + t0] = pk;
                } else {
                    float sc = (which == 0) ? QSCALE : 1.0f;
                    size_t base = (size_t)which * per + (((size_t)(b * Hn + h) * Tn + t0) * Dn) + d;
                    #pragma unroll
                    for (int r = 0; r < 4; ++r)
                        outb[base + (size_t)r * Dn] = f2bf(acc[i][j][r] * sc);
                }
            }
        }
    } else {
        #pragma unroll
        for (int i = 0; i < 4; ++i) {
            #pragma unroll
            for (int r = 0; r < 4; ++r) {
                int mrow = m0 + i * 16 + g * 4 + r;
                #pragma unroll
                for (int j = 0; j < 4; ++j)
                    outf[(size_t)mrow * Cn + n0 + j * 16 + m] = acc[i][j][r];
            }
        }
    }
}

// ---------------------------------------------------------------------------
// Flash attention via S^T, no-max softmax, bf16 MFMA.
// Q-tile 128 per block, 512 threads (8 waves x 16 queries). K-tile 64, double-
// buffered async global_load_lds staging into lane-linear segments.
// P^T -> PV B-frag transform done IN-REGISTER via ds_bpermute (no P LDS array):
// target lane (m,g), kc pulls P-pair dwords from lanes 32(g&1)+m and +16 with
// t = 2kc+(g>>1) selected by cndmask. LDS = 44KB -> 3 blocks/CU.
// ---------------------------------------------------------------------------
__global__ __launch_bounds__(512, 6)
void attn_mfma(const ushort_t* __restrict__ Q, const ushort_t* __restrict__ K,
               const ushort_t* __restrict__ V, ushort_t* __restrict__ Y,
               const ushort_t* __restrict__ zb)
{
    __shared__ __align__(16) ushort_t Qs[16][512];     // (wave w, kc): q rows w*16..+15
    __shared__ __align__(16) ushort_t Ks[2][8][512];   // [buf][(ktile t, kc)]
    __shared__ __align__(16) ushort_t Vs[2][6][512];   // [buf][(dtile t, kc)]

    const int QT   = gridDim.x - 1 - blockIdx.x;       // big tiles dispatch first
    const int bh   = blockIdx.y;
    const int tid  = threadIdx.x;
    const int wave = tid >> 6;       // 0..7
    const int lane = tid & 63;
    const int m    = lane & 15;
    const int g    = lane >> 4;
    const int q0   = QT * 128;
    const int nkt  = 2 * QT + 2;     // 64-row K tiles to process

    const ushort_t* Qp = Q + (size_t)bh * Tn * Dn;
    const ushort_t* Kp = K + (size_t)bh * Tn * Dn;
    const ushort_t* Vp = V + (size_t)bh * Dn * Tn;     // [48][T]

    // ---- Q staging: wave w stages segs 2w,2w+1 (rows q0+w*16+m); pad -> zeros ----
    {
        const char* qrp = (const char*)(Qp + (size_t)(q0 + wave * 16 + m) * Dn);
        gload16(&Qs[wave * 2 + 0][0], qrp + g * 16);
        gload16(&Qs[wave * 2 + 1][0], (g < 2) ? (qrp + 64 + g * 16) : (const char*)zb);
    }

    // ---- per-lane K/V staging pointers (wave w owns K seg w; V seg w for w<6) ----
    const bool  kpad = ((wave & 1) == 1) && (g >= 2);
    const char* kptr = kpad ? (const char*)zb
        : (const char*)(Kp + (size_t)((wave >> 1) * 16 + m) * Dn) + (wave & 1) * 64 + g * 16;
    const int   kadv = kpad ? 0 : 64 * Dn * 2;         // 64 K-rows per tile
    const char* vptr = (const char*)(Vp + (size_t)((wave >> 1) * 16 + m) * Tn)
                       + (wave & 1) * 64 + g * 16;     // valid only for wave<6
    const int   vadv = 64 * 2;                         // 64 V^T-cols per tile

    // prologue: stage K/V tile 0 into buf 0
    gload16(&Ks[0][wave][0], kptr); kptr += kadv;
    if (wave < 6) { gload16(&Vs[0][wave][0], vptr); vptr += vadv; }
    __syncthreads();   // drains vmcnt -> Q + tile0 ready

    // loop-invariant B-fragments (Q): B[n=q=wave*16+m][k=d]
    short8 bq[2];
    bq[0] = *(const short8*)&Qs[wave * 2 + 0][lane * 8];
    bq[1] = *(const short8*)&Qs[wave * 2 + 1][lane * 8];

    floatx4 acc[3];
    #pragma unroll
    for (int t = 0; t < 3; ++t) acc[t] = (floatx4){0.f, 0.f, 0.f, 0.f};
    float l_tot = 0.f;
    const int qrow  = q0 + wave * 16 + m;    // this lane's global query row
    const int qwmin = q0 + wave * 16;        // wave's min query row
    const int qwmax = qwmin + 15;            // wave's max query row

    // bpermute source lanes for the P^T -> B-frag transform
    const int addrA = ((g & 1) * 32 + m) << 2;
    const int addrB = addrA + (16 << 2);
    const bool hi   = (g & 2);

    for (int jt = 0; jt < nkt; ++jt) {
        const int cur = jt & 1;
        const int j0  = jt * 64;
        // issue async staging for tile jt+1 (overlaps this tile's compute)
        if (jt + 1 < nkt) {
            gload16(&Ks[cur ^ 1][wave][0], kptr); kptr += kadv;
            if (wave < 6) { gload16(&Vs[cur ^ 1][wave][0], vptr); vptr += vadv; }
        }

        if (j0 <= qwmax) {   // wave-uniform: at least one unmasked element
            // ---- S^T = K Q^T : D[m=j (4 tiles)][n=q] ----
            floatx4 s[4];
            #pragma unroll
            for (int t = 0; t < 4; ++t) {
                s[t] = (floatx4){0.f, 0.f, 0.f, 0.f};
                #pragma unroll
                for (int kc = 0; kc < 2; ++kc) {
                    short8 ak = *(const short8*)&Ks[cur][t * 2 + kc][lane * 8];
                    s[t] = __builtin_amdgcn_mfma_f32_16x16x32_bf16(ak, bq[kc], s[t], 0, 0, 0);
                }
            }

            // ---- mask (only if tile straddles diagonal) + exp2 + partial row-sum ----
            float p[4][4];
            float lsum = 0.f;
            if (j0 + 63 > qwmin) {
                #pragma unroll
                for (int t = 0; t < 4; ++t)
                    #pragma unroll
                    for (int r = 0; r < 4; ++r) {
                        int j = j0 + t * 16 + g * 4 + r;
                        float v = (j <= qrow) ? s[t][r] : -1e30f;
                        float e = __builtin_amdgcn_exp2f(v);
                        p[t][r] = e; lsum += e;
                    }
            } else {
                #pragma unroll
                for (int t = 0; t < 4; ++t)
                    #pragma unroll
                    for (int r = 0; r < 4; ++r) {
                        float e = __builtin_amdgcn_exp2f(s[t][r]);
                        p[t][r] = e; lsum += e;
                    }
            }
            lsum += __shfl_xor(lsum, 16);
            lsum += __shfl_xor(lsum, 32);
            l_tot += lsum;

            // ---- pack P^T pairs; in-register transform to PV B-frag layout ----
            int P0[4], P1[4];
            #pragma unroll
            for (int t = 0; t < 4; ++t) {
                P0[t] = (int)pack_trunc(p[t][0], p[t][1]);   // j = 16t+4g_s+{0,1}
                P1[t] = (int)pack_trunc(p[t][2], p[t][3]);   // j = 16t+4g_s+{2,3}
            }

            // ---- O^T += V^T P^T : D[m=d (3 tiles)][n=q] ----
            #pragma unroll
            for (int kc = 0; kc < 2; ++kc) {
                int d0a = __builtin_amdgcn_ds_bpermute(addrA, P0[2 * kc + 0]);
                int d0b = __builtin_amdgcn_ds_bpermute(addrA, P0[2 * kc + 1]);
                int d1a = __builtin_amdgcn_ds_bpermute(addrA, P1[2 * kc + 0]);
                int d1b = __builtin_amdgcn_ds_bpermute(addrA, P1[2 * kc + 1]);
                int d2a = __builtin_amdgcn_ds_bpermute(addrB, P0[2 * kc + 0]);
                int d2b = __builtin_amdgcn_ds_bpermute(addrB, P0[2 * kc + 1]);
                int d3a = __builtin_amdgcn_ds_bpermute(addrB, P1[2 * kc + 0]);
                int d3b = __builtin_amdgcn_ds_bpermute(addrB, P1[2 * kc + 1]);
                union { int u[4]; short8 v; } bp;
                bp.u[0] = hi ? d0b : d0a;
                bp.u[1] = hi ? d1b : d1a;
                bp.u[2] = hi ? d2b : d2a;
                bp.u[3] = hi ? d3b : d3a;
                #pragma unroll
                for (int t = 0; t < 3; ++t) {
                    short8 av = *(const short8*)&Vs[cur][t * 2 + kc][lane * 8];
                    acc[t] = __builtin_amdgcn_mfma_f32_16x16x32_bf16(av, bp.v, acc[t], 0, 0, 0);
                }
            }
        }

        __syncthreads();   // next tile staged (vmcnt drain) + cur-buf reads done
    }

    // ---- epilogue: lane holds O^T[d = t*16+g*4+r][qrow]; normalize, store ----
    const float inv = 1.0f / l_tot;
    const int b = bh / Hn;
    const int h = bh - b * Hn;
    ushort_t* yp = Y + ((size_t)(b * Tn + qrow)) * Cn + h * Dn;
    #pragma unroll
    for (int t = 0; t < 3; ++t) {
        ushort4 o;
        o.x = f2bf(acc[t][0] * inv);
        o.y = f2bf(acc[t][1] * inv);
        o.z = f2bf(acc[t][2] * inv);
        o.w = f2bf(acc[t][3] * inv);
        *(ushort4*)&yp[t * 16 + g * 4] = o;
    }
}

// ---------------------------------------------------------------------------
extern "C" void kernel_launch(void* const* d_in, const int* in_sizes, int n_in,
                              void* d_out, int out_size, void* d_ws, size_t ws_size,
                              hipStream_t stream)
{
    const float* x      = (const float*)d_in[0];   // [B,T,C]
    const float* w_qkv  = (const float*)d_in[1];   // [3C,C]
    const float* w_proj = (const float*)d_in[2];   // [C,C]
    float* out = (float*)d_out;                    // [B,T,C] fp32

    const size_t per = (size_t)Bn * Hn * Tn * Dn;  // 4,718,592

    ushort_t* xb  = (ushort_t*)d_ws;               // 8192*576
    ushort_t* wqb = xb  + (size_t)Mn * Cn;         // 1728*576
    ushort_t* wpb = wqb + (size_t)3 * Cn * Cn;     // 576*576
    ushort_t* qkv = wpb + (size_t)Cn * Cn;         // 3*per (q | k | v^T)
    ushort_t* yb  = qkv + 3 * per;                 // 8192*576
    ushort_t* zb  = yb  + (size_t)Mn * Cn;         // 256 B of zeros (Q/K pad source)

    hipMemsetAsync(zb, 0, 256, stream);

    // fused casts (fp32 -> bf16)
    const int na4 = Mn * Cn / 4, nb4 = 3 * Cn * Cn / 4, nc4 = Cn * Cn / 4;
    cast3<<<dim3((na4 + nb4 + nc4 + 255) / 256), dim3(256), 0, stream>>>(
        x, xb, na4, w_qkv, wqb, nb4, w_proj, wpb, nc4);

    // QKV GEMM (M=8192, N=1728): 3456 wave-tiles / 2 per block
    gemm_mfma<0, 27><<<dim3((Mn / 64) * 27 / 2), dim3(128), 0, stream>>>(xb, wqb, qkv, nullptr);

    // causal attention (ALiBi bias is exactly zero on the unmasked region)
    attn_mfma<<<dim3(Tn / 128, Bn * Hn), dim3(512), 0, stream>>>(qkv, qkv + per, qkv + 2 * per, yb, zb);

    // output projection (M=8192, N=576) -> fp32: 1152 wave-tiles / 2 per block
    gemm_mfma<1, 9><<<dim3((Mn / 64) * 9 / 2), dim3(128), 0, stream>>>(yb, wpb, nullptr, out);
}

// Round 7
// 207.798 us; speedup vs baseline: 1.2128x; 1.2128x over previous
//
#include <hip/hip_runtime.h>
#include <math.h>

// Problem constants (B=4, T=2048, C=576, H=12, D=48)
#define Bn 4
#define Tn 2048
#define Cn 576
#define Hn 12
#define Dn 48
#define Mn (Bn*Tn)          // 8192 rows

// log2(e) / sqrt(48) — folded into q so attention uses exp2 directly
#define QSCALE (1.4426950408889634f * 0.14433756729740643f)

typedef short  short8  __attribute__((ext_vector_type(8)));   // 8 bf16 (4 VGPRs)
typedef float  floatx4 __attribute__((ext_vector_type(4)));   // MFMA acc
typedef unsigned short ushort_t;

static __device__ __forceinline__ unsigned short f2bf(float f) {
    union { float f; unsigned int u; } v; v.f = f;
    unsigned int r = v.u + 0x7FFFu + ((v.u >> 16) & 1u);   // round-to-nearest-even
    return (unsigned short)(r >> 16);
}

// truncation-pack two fp32 -> packed bf16x2 (P >= 0, rel err <= 2^-8)
static __device__ __forceinline__ unsigned int pack_trunc(float a, float b) {
    union { float f; unsigned int u; } ua, ub; ua.f = a; ub.f = b;
    return (ua.u >> 16) | (ub.u & 0xFFFF0000u);
}

// async global->LDS, 16B per lane; lane l's data lands at lds + l*16 (lane-linear)
static __device__ __forceinline__ void gload16(void* lds, const void* g) {
    __builtin_amdgcn_global_load_lds(
        (const __attribute__((address_space(1))) void*)g,
        (__attribute__((address_space(3))) void*)lds, 16, 0, 0);
}

// ---------------------------------------------------------------------------
// fused fp32 -> bf16 cast of all three inputs (one launch)
// ---------------------------------------------------------------------------
__global__ __launch_bounds__(256)
void cast3(const float* __restrict__ a, ushort_t* __restrict__ oa, int na4,
           const float* __restrict__ b, ushort_t* __restrict__ ob, int nb4,
           const float* __restrict__ c, ushort_t* __restrict__ oc, int nc4)
{
    int i = blockIdx.x * 256 + threadIdx.x;
    const float* src; ushort_t* dst; int idx;
    if (i < na4)                  { src = a; dst = oa; idx = i; }
    else if (i < na4 + nb4)       { src = b; dst = ob; idx = i - na4; }
    else if (i < na4 + nb4 + nc4) { src = c; dst = oc; idx = i - na4 - nb4; }
    else return;
    float4 v = ((const float4*)src)[idx];
    ushort4 o;
    o.x = f2bf(v.x); o.y = f2bf(v.y); o.z = f2bf(v.z); o.w = f2bf(v.w);
    ((ushort4*)dst)[idx] = o;
}

// ---------------------------------------------------------------------------
// MFMA bf16 GEMM: out = A[M,576] @ W[N,576]^T, DOUBLE-BUFFERED LDS (round-5
// structure: issue next K-step's global_load_lds, compute current, barrier).
// Block tile MTILE(M) x 64(N), BK=32, 4 waves stacked in M.
// LDS segment-linear (1KB seg = 16 rows x 32 cols in exact MFMA A-frag order).
// 1D grid, n fastest (bid%NB) for L2 reuse of A rows across the n sweep.
// MODE 0: scatter q (xQSCALE) / k -> [B,H,T,48]; v -> transposed [B,H,48,T]
// MODE 1: fp32 row-major [M,576]
// ---------------------------------------------------------------------------
template<int MODE, int MTILE>
__global__ __launch_bounds__(256)
void gemm_mfma(const ushort_t* __restrict__ A, const ushort_t* __restrict__ W,
               ushort_t* __restrict__ outb, float* __restrict__ outf)
{
    constexpr int SA   = MTILE / 16;      // A segments
    constexpr int NSEG = SA + 4;          // + B segments (NTILE=64)
    constexpr int PW   = NSEG / 4;        // staging loads per wave per K-step
    constexpr int MF   = MTILE / 64;      // m-frags per wave
    constexpr int NB   = (MODE == 0) ? 27 : 9;
    __shared__ __align__(16) ushort_t Ls[2][NSEG][512];

    const int tid  = threadIdx.x;
    const int wave = tid >> 6;
    const int lane = tid & 63;
    const int m    = lane & 15;
    const int g    = lane >> 4;
    const int bid  = blockIdx.x;
    const int n0   = (bid % NB) * 64;
    const int m0   = (bid / NB) * MTILE;

    floatx4 acc[MF][4];
    #pragma unroll
    for (int i = 0; i < MF; ++i)
        #pragma unroll
        for (int j = 0; j < 4; ++j)
            acc[i][j] = (floatx4){0.f, 0.f, 0.f, 0.f};

    const char* gp[PW];
    int         si[PW];
    #pragma unroll
    for (int i = 0; i < PW; ++i) {
        int s = wave + i * 4;
        si[i] = s;
        gp[i] = (s < SA)
            ? (const char*)(A + (size_t)(m0 + s * 16 + m) * Cn + g * 8)
            : (const char*)(W + (size_t)(n0 + (s - SA) * 16 + m) * Cn + g * 8);
    }

    // prologue: stage K-step 0 into buf 0
    #pragma unroll
    for (int i = 0; i < PW; ++i) { gload16(&Ls[0][si[i]][0], gp[i]); gp[i] += 64; }
    __syncthreads();

    int buf = 0;
    for (int k0 = 0; k0 < Cn; k0 += 32) {
        if (k0 + 32 < Cn) {     // issue next K-step into the other buffer (async)
            #pragma unroll
            for (int i = 0; i < PW; ++i) { gload16(&Ls[buf ^ 1][si[i]][0], gp[i]); gp[i] += 64; }
        }
        short8 bf4[4];
        #pragma unroll
        for (int j = 0; j < 4; ++j) bf4[j] = *(const short8*)&Ls[buf][SA + j][lane * 8];
        #pragma unroll
        for (int i = 0; i < MF; ++i) {
            short8 af = *(const short8*)&Ls[buf][wave * MF + i][lane * 8];
            #pragma unroll
            for (int j = 0; j < 4; ++j)
                acc[i][j] = __builtin_amdgcn_mfma_f32_16x16x32_bf16(af, bf4[j], acc[i][j], 0, 0, 0);
        }
        __syncthreads();        // drains vmcnt -> next buf ready; protects overwrite
        buf ^= 1;
    }

    // epilogue: C/D layout col = lane&15 (n), row = (lane>>4)*4 + reg (m)
    const size_t per = (size_t)Bn * Hn * Tn * Dn;
    if (MODE == 0) {
        const int which = n0 / Cn;                 // 64-col block fits in one of q/k/v
        const int nb    = n0 - which * Cn;
        #pragma unroll
        for (int i = 0; i < MF; ++i) {
            int mrow0 = m0 + wave * (MTILE / 4) + i * 16 + g * 4;
            int b  = mrow0 >> 11;
            int t0 = mrow0 & 2047;
            #pragma unroll
            for (int j = 0; j < 4; ++j) {
                int n = nb + j * 16 + m;
                int h = n / 48;
                int d = n - h * 48;
                if (which == 2) {
                    ushort4 pk;
                    pk.x = f2bf(acc[i][j][0]); pk.y = f2bf(acc[i][j][1]);
                    pk.z = f2bf(acc[i][j][2]); pk.w = f2bf(acc[i][j][3]);
                    *(ushort4*)&outb[2 * per + (((size_t)(b * Hn + h) * Dn + d) * Tn) + t0] = pk;
                } else {
                    float sc = (which == 0) ? QSCALE : 1.0f;
                    size_t base = (size_t)which * per + (((size_t)(b * Hn + h) * Tn + t0) * Dn) + d;
                    #pragma unroll
                    for (int r = 0; r < 4; ++r)
                        outb[base + (size_t)r * Dn] = f2bf(acc[i][j][r] * sc);
                }
            }
        }
    } else {
        #pragma unroll
        for (int i = 0; i < MF; ++i) {
            #pragma unroll
            for (int r = 0; r < 4; ++r) {
                int mrow = m0 + wave * (MTILE / 4) + i * 16 + g * 4 + r;
                #pragma unroll
                for (int j = 0; j < 4; ++j)
                    outf[(size_t)mrow * Cn + n0 + j * 16 + m] = acc[i][j][r];
            }
        }
    }
}

// ---------------------------------------------------------------------------
// Flash attention via S^T, no-max softmax, bf16 MFMA (round-5 compute path).
// Q-tile 128 per block, 512 threads (8 waves x 16 queries). K-tile 64, double-
// buffered async global_load_lds staging into lane-linear segments.
// OCCUPANCY FIX: Ps aliases Qs (QPs). Both are wave-private strips with the
// same segment assignment (wave w owns segs 2w,2w+1); bq is register-resident
// before the first Ps write, and in-wave DS ordering covers the read->write
// hazard. LDS 60KB -> 44KB -> 3 blocks/CU (24 waves).
// ---------------------------------------------------------------------------
__global__ __launch_bounds__(512, 6)
void attn_mfma(const ushort_t* __restrict__ Q, const ushort_t* __restrict__ K,
               const ushort_t* __restrict__ V, ushort_t* __restrict__ Y,
               const ushort_t* __restrict__ zb)
{
    __shared__ __align__(16) ushort_t QPs[16][512];    // Q tile, then reused as P^T
    __shared__ __align__(16) ushort_t Ks[2][8][512];   // [buf][(ktile t, kc)]
    __shared__ __align__(16) ushort_t Vs[2][6][512];   // [buf][(dtile t, kc)]

    const int QT   = gridDim.x - 1 - blockIdx.x;       // big tiles dispatch first
    const int bh   = blockIdx.y;
    const int tid  = threadIdx.x;
    const int wave = tid >> 6;       // 0..7
    const int lane = tid & 63;
    const int m    = lane & 15;
    const int g    = lane >> 4;
    const int q0   = QT * 128;
    const int nkt  = 2 * QT + 2;     // 64-row K tiles to process

    const ushort_t* Qp = Q + (size_t)bh * Tn * Dn;
    const ushort_t* Kp = K + (size_t)bh * Tn * Dn;
    const ushort_t* Vp = V + (size_t)bh * Dn * Tn;     // [48][T]

    // ---- Q staging: wave w stages segs 2w,2w+1 (rows q0+w*16+m); pad -> zeros ----
    {
        const char* qrp = (const char*)(Qp + (size_t)(q0 + wave * 16 + m) * Dn);
        gload16(&QPs[wave * 2 + 0][0], qrp + g * 16);
        gload16(&QPs[wave * 2 + 1][0], (g < 2) ? (qrp + 64 + g * 16) : (const char*)zb);
    }

    // ---- per-lane K/V staging pointers (wave w owns K seg w; V seg w for w<6) ----
    const bool  kpad = ((wave & 1) == 1) && (g >= 2);
    const char* kptr = kpad ? (const char*)zb
        : (const char*)(Kp + (size_t)((wave >> 1) * 16 + m) * Dn) + (wave & 1) * 64 + g * 16;
    const int   kadv = kpad ? 0 : 64 * Dn * 2;         // 64 K-rows per tile
    const char* vptr = (const char*)(Vp + (size_t)((wave >> 1) * 16 + m) * Tn)
                       + (wave & 1) * 64 + g * 16;     // valid only for wave<6
    const int   vadv = 64 * 2;                         // 64 V^T-cols per tile

    // prologue: stage K/V tile 0 into buf 0
    gload16(&Ks[0][wave][0], kptr); kptr += kadv;
    if (wave < 6) { gload16(&Vs[0][wave][0], vptr); vptr += vadv; }
    __syncthreads();   // drains vmcnt -> Q + tile0 ready

    // loop-invariant B-fragments (Q): B[n=q=wave*16+m][k=d]; after this QPs
    // strip (wave-private) is dead as Q and is reused for P^T.
    short8 bq[2];
    bq[0] = *(const short8*)&QPs[wave * 2 + 0][lane * 8];
    bq[1] = *(const short8*)&QPs[wave * 2 + 1][lane * 8];

    floatx4 acc[3];
    #pragma unroll
    for (int t = 0; t < 3; ++t) acc[t] = (floatx4){0.f, 0.f, 0.f, 0.f};
    float l_tot = 0.f;
    const int qrow  = q0 + wave * 16 + m;    // this lane's global query row
    const int qwmin = q0 + wave * 16;        // wave's min query row
    const int qwmax = qwmin + 15;            // wave's max query row

    for (int jt = 0; jt < nkt; ++jt) {
        const int cur = jt & 1;
        const int j0  = jt * 64;
        // issue async staging for tile jt+1 (overlaps this tile's compute)
        if (jt + 1 < nkt) {
            gload16(&Ks[cur ^ 1][wave][0], kptr); kptr += kadv;
            if (wave < 6) { gload16(&Vs[cur ^ 1][wave][0], vptr); vptr += vadv; }
        }

        if (j0 <= qwmax) {   // wave-uniform: at least one unmasked element
            // ---- S^T = K Q^T : D[m=j (4 tiles)][n=q] ----
            floatx4 s[4];
            #pragma unroll
            for (int t = 0; t < 4; ++t) {
                s[t] = (floatx4){0.f, 0.f, 0.f, 0.f};
                #pragma unroll
                for (int kc = 0; kc < 2; ++kc) {
                    short8 ak = *(const short8*)&Ks[cur][t * 2 + kc][lane * 8];
                    s[t] = __builtin_amdgcn_mfma_f32_16x16x32_bf16(ak, bq[kc], s[t], 0, 0, 0);
                }
            }

            // ---- mask (only if tile straddles diagonal) + exp2 + partial row-sum ----
            float p[4][4];
            float lsum = 0.f;
            if (j0 + 63 > qwmin) {
                #pragma unroll
                for (int t = 0; t < 4; ++t)
                    #pragma unroll
                    for (int r = 0; r < 4; ++r) {
                        int j = j0 + t * 16 + g * 4 + r;
                        float v = (j <= qrow) ? s[t][r] : -1e30f;
                        float e = __builtin_amdgcn_exp2f(v);
                        p[t][r] = e; lsum += e;
                    }
            } else {
                #pragma unroll
                for (int t = 0; t < 4; ++t)
                    #pragma unroll
                    for (int r = 0; r < 4; ++r) {
                        float e = __builtin_amdgcn_exp2f(s[t][r]);
                        p[t][r] = e; lsum += e;
                    }
            }
            lsum += __shfl_xor(lsum, 16);
            lsum += __shfl_xor(lsum, 32);
            l_tot += lsum;

            // ---- store P^T in B-frag order into the (dead) Q strip ----
            #pragma unroll
            for (int t = 0; t < 4; ++t) {
                uint2 w2;
                w2.x = pack_trunc(p[t][0], p[t][1]);
                w2.y = pack_trunc(p[t][2], p[t][3]);
                *(uint2*)&QPs[wave * 2 + (t >> 1)]
                             [(2 * (t & 1) + (g >> 1)) * 128 + m * 8 + (g & 1) * 4] = w2;
            }
            // wave-private strip: drain this wave's LDS writes, no barrier needed
            asm volatile("s_waitcnt lgkmcnt(0)" ::: "memory");

            // ---- O^T += V^T P^T : D[m=d (3 tiles)][n=q] ----
            #pragma unroll
            for (int kc = 0; kc < 2; ++kc) {
                short8 bp = *(const short8*)&QPs[wave * 2 + kc][lane * 8];
                #pragma unroll
                for (int t = 0; t < 3; ++t) {
                    short8 av = *(const short8*)&Vs[cur][t * 2 + kc][lane * 8];
                    acc[t] = __builtin_amdgcn_mfma_f32_16x16x32_bf16(av, bp, acc[t], 0, 0, 0);
                }
            }
        }

        __syncthreads();   // next tile staged (vmcnt drain) + cur-buf reads done
    }

    // ---- epilogue: lane holds O^T[d = t*16+g*4+r][qrow]; normalize, store ----
    const float inv = 1.0f / l_tot;
    const int b = bh / Hn;
    const int h = bh - b * Hn;
    ushort_t* yp = Y + ((size_t)(b * Tn + qrow)) * Cn + h * Dn;
    #pragma unroll
    for (int t = 0; t < 3; ++t) {
        ushort4 o;
        o.x = f2bf(acc[t][0] * inv);
        o.y = f2bf(acc[t][1] * inv);
        o.z = f2bf(acc[t][2] * inv);
        o.w = f2bf(acc[t][3] * inv);
        *(ushort4*)&yp[t * 16 + g * 4] = o;
    }
}

// ---------------------------------------------------------------------------
extern "C" void kernel_launch(void* const* d_in, const int* in_sizes, int n_in,
                              void* d_out, int out_size, void* d_ws, size_t ws_size,
                              hipStream_t stream)
{
    const float* x      = (const float*)d_in[0];   // [B,T,C]
    const float* w_qkv  = (const float*)d_in[1];   // [3C,C]
    const float* w_proj = (const float*)d_in[2];   // [C,C]
    float* out = (float*)d_out;                    // [B,T,C] fp32

    const size_t per = (size_t)Bn * Hn * Tn * Dn;  // 4,718,592

    ushort_t* xb  = (ushort_t*)d_ws;               // 8192*576
    ushort_t* wqb = xb  + (size_t)Mn * Cn;         // 1728*576
    ushort_t* wpb = wqb + (size_t)3 * Cn * Cn;     // 576*576
    ushort_t* qkv = wpb + (size_t)Cn * Cn;         // 3*per (q | k | v^T)
    ushort_t* yb  = qkv + 3 * per;                 // 8192*576
    ushort_t* zb  = yb  + (size_t)Mn * Cn;         // 256 B of zeros (Q/K pad source)

    hipMemsetAsync(zb, 0, 256, stream);

    // fused casts (fp32 -> bf16)
    const int na4 = Mn * Cn / 4, nb4 = 3 * Cn * Cn / 4, nc4 = Cn * Cn / 4;
    cast3<<<dim3((na4 + nb4 + nc4 + 255) / 256), dim3(256), 0, stream>>>(
        x, xb, na4, w_qkv, wqb, nb4, w_proj, wpb, nc4);

    // QKV GEMM (M=8192, N=1728): q scaled, k natural, v transposed; 864 blocks
    gemm_mfma<0, 256><<<dim3((Mn / 256) * 27), dim3(256), 0, stream>>>(xb, wqb, qkv, nullptr);

    // causal attention (ALiBi bias is exactly zero on the unmasked region)
    attn_mfma<<<dim3(Tn / 128, Bn * Hn), dim3(512), 0, stream>>>(qkv, qkv + per, qkv + 2 * per, yb, zb);

    // output projection (M=8192, N=576) -> fp32; 576 blocks
    gemm_mfma<1, 128><<<dim3((Mn / 128) * 9), dim3(256), 0, stream>>>(yb, wpb, nullptr, out);
}